// Round 4
// baseline (487.624 us; speedup 1.0000x reference)
//
#include <hip/hip_runtime.h>

// ComplexMultiheadAttention on MI355X (gfx950)  B=2, L=2048, E=1024, H=16, D=64
// R10: attn only (gemm_qkv/oproj/convs unchanged from R9).
// (a) XCD-locality block swizzle: grid flattened to 1024; bid -> xcd=bid&7,
//     bh = xcd + 8*(j>>5), q0 = (j&31)*64 (bijective). All 32 q-blocks of a
//     bh land on ONE XCD (consecutive bids round-robin XCDs), so each bh's
//     K/V panel (1 MB) is fetched into one L2 once instead of 8 -- kills the
//     measured 8x HBM over-fetch (139 MB vs ~17 MB of K+V) and converts
//     K/V reads to L2 hits (~200cy vs ~900cy) in this latency-bound kernel.
// (b) P-pack via v_cvt_pk_bf16_f32 (hardware RNE, bit-identical to f2bf for
//     finite values): 8 cvt_pk replace 16 scalar f2bf (~40 VALU ops/tile/lane
//     off the softmax->PV critical path).
// Softmax math otherwise VERBATIM (known good, absmax 0.0390625).

#define LL 2048
#define EE 1024
#define HH 16
#define BL 4096   // B*L
#define KK 2048   // GEMM K (re||im)

typedef __attribute__((ext_vector_type(8))) short bf16x8;
typedef __attribute__((ext_vector_type(4))) float f32x4;
typedef unsigned short u16;

__device__ __forceinline__ u16 f2bf(float x) {
    unsigned u = __builtin_bit_cast(unsigned, x);
    u += 0x7fff + ((u >> 16) & 1);          // RNE
    return (u16)(u >> 16);
}

__device__ __forceinline__ void gl2lds16(const void* g, void* l) {
    __builtin_amdgcn_global_load_lds((const __attribute__((address_space(1))) void*)g,
                                     (__attribute__((address_space(3))) void*)l, 16, 0, 0);
}

// ---------------------------------------------------------------------------
// Merged fp32->bf16 conversion: 6 activation tensors, grid (4096, 6)
// ---------------------------------------------------------------------------
struct ConvXArgs { const float* src[6]; u16* dst[6]; };
__global__ void conv_x(ConvXArgs a) {
    const int z = blockIdx.y;
    int i = blockIdx.x * 256 + threadIdx.x;     // 1,048,576 float4 groups exactly
    float4 v = ((const float4*)a.src[z])[i];
    ushort4 o;
    o.x = f2bf(v.x); o.y = f2bf(v.y); o.z = f2bf(v.z); o.w = f2bf(v.w);
    ((ushort4*)a.dst[z])[i] = o;
}

// ---------------------------------------------------------------------------
// Merged W2 build: 4 weight pairs, grid (4096, 4)
// W2 bf16 [2048 n][2048 k]: n<1024: [Wr | -Wi] ; n>=1024: [Wi | Wr]
// ---------------------------------------------------------------------------
struct ConvWArgs { const float* wr[4]; const float* wi[4]; u16* w2[4]; };
__global__ void conv_w(ConvWArgs a) {
    const int z = blockIdx.y;
    int i = blockIdx.x * 256 + threadIdx.x;     // 2048*512 groups exactly
    int n = i >> 9, k = (i & 511) << 2;
    bool nh = n >= EE, kh = k >= EE;
    int nn = n & (EE - 1), kk = k & (EE - 1);
    const float* src = nh ? (kh ? a.wr[z] : a.wi[z]) : (kh ? a.wi[z] : a.wr[z]);
    float sgn = (!nh && kh) ? -1.0f : 1.0f;
    float4 v = *(const float4*)(src + nn * EE + kk);
    ushort4 o;
    o.x = f2bf(v.x * sgn); o.y = f2bf(v.y * sgn);
    o.z = f2bf(v.z * sgn); o.w = f2bf(v.w * sgn);
    *(ushort4*)(a.w2[z] + n * KK + k) = o;
}

// ---------------------------------------------------------------------------
// Shared 128x256 triple-buffered GEMM K-loop (R9, unchanged).
// LDS: As3[3][128*64] (16 KB/buf) + Bs3[3][256*64] (32 KB/buf) = 144 KiB.
// 512 threads = 8 waves as 2M x 4N; wave tile 64x64 = acc[4][4].
// ---------------------------------------------------------------------------
#define BAR      asm volatile("s_barrier" ::: "memory")
#define BARW(N)  asm volatile("s_waitcnt vmcnt(" #N ")\n\ts_barrier" ::: "memory")

#define S_A(B, K0)                                                             \
    { const u16* S_ = ((K0) < EE) ? (Apr + (K0)) : (Api + ((K0) - EE));        \
      int rl_ = wv * 8 + (lane >> 3);                                          \
      int cg_ = ((lane & 7) ^ (lane >> 3)) * 8;                                \
      gl2lds16(S_ + (size_t)(m0 + rl_) * EE + cg_, &As3[B][wv * 512]);         \
      gl2lds16(S_ + (size_t)(m0 + rl_ + 64) * EE + cg_, &As3[B][wv * 512 + 4096]); }

#define S_B(B, H, K0)                                                          \
    { const u16* S_ = Bp + (K0);                                               \
      int rl_ = wv * 8 + (lane >> 3);                                          \
      int cg_ = ((lane & 7) ^ (lane >> 3)) * 8;                                \
      gl2lds16(S_ + (size_t)(n0 + (H) * 128 + rl_) * (size_t)KK + cg_,         \
               &Bs3[B][(H) * 8192 + wv * 512]);                                \
      gl2lds16(S_ + (size_t)(n0 + (H) * 128 + rl_ + 64) * (size_t)KK + cg_,    \
               &Bs3[B][(H) * 8192 + wv * 512 + 4096]); }

#define L_A(B)                                                                 \
    _Pragma("unroll") for (int i_ = 0; i_ < 4; i_++) {                         \
        int row_ = wr * 64 + i_ * 16 + l16;                                    \
        _Pragma("unroll") for (int s_ = 0; s_ < 2; s_++) {                     \
            int ph_ = (s_ * 4 + quad) ^ (l16 & 7);                             \
            afr[i_][s_] = *(const bf16x8*)&As3[B][row_ * 64 + ph_ * 8]; } }

#define L_B(B, H)                                                              \
    _Pragma("unroll") for (int j_ = 0; j_ < 2; j_++) {                         \
        int row_ = wc * 32 + j_ * 16 + l16;                                    \
        _Pragma("unroll") for (int s_ = 0; s_ < 2; s_++) {                     \
            int ph_ = (s_ * 4 + quad) ^ (l16 & 7);                             \
            bfr[j_][s_] = *(const bf16x8*)&Bs3[B][(H) * 8192 + row_ * 64 + ph_ * 8]; } }

#define MMA_H(H)                                                               \
    { __builtin_amdgcn_s_setprio(1);                                           \
      _Pragma("unroll") for (int s_ = 0; s_ < 2; s_++)                         \
          _Pragma("unroll") for (int i_ = 0; i_ < 4; i_++)                     \
              _Pragma("unroll") for (int j_ = 0; j_ < 2; j_++)                 \
                  acc[i_][(H) * 2 + j_] =                                      \
                      __builtin_amdgcn_mfma_f32_16x16x32_bf16(                 \
                          afr[i_][s_], bfr[j_][s_], acc[i_][(H) * 2 + j_], 0, 0, 0); \
      __builtin_amdgcn_s_setprio(0); }

#define GITER(B, NB, KN)                                                       \
    {   L_A(B); L_B(B, 0);                                                     \
        S_A(NB, KN); S_B(NB, 0, KN);                                           \
        BAR;                                                                   \
        MMA_H(0);                                                              \
        L_B(B, 1);                                                             \
        S_B(NB, 1, KN);                                                        \
        BAR;                                                                   \
        MMA_H(1);                                                              \
        BARW(6); }

#define GEMM3_LOOP                                                             \
    S_A(0, 0);  S_B(0, 0, 0);  S_B(0, 1, 0);                                   \
    S_A(1, 64); S_B(1, 0, 64); S_B(1, 1, 64);                                  \
    BARW(6);                                                                   \
    for (int t3 = 0; t3 < 10; t3++) {                                          \
        const int kb = t3 * 192;                                               \
        GITER(0, 2, kb + 128);                                                 \
        GITER(1, 0, kb + 192);                                                 \
        GITER(2, 1, kb + 256);                                                 \
    }                                                                          \
    { L_A(0); L_B(0, 0); MMA_H(0); L_B(0, 1); MMA_H(1); }                      \
    BARW(0);                                                                   \
    { L_A(1); L_B(1, 0); MMA_H(0); L_B(1, 1); MMA_H(1); }

// ---------------------------------------------------------------------------
// Merged Q/K/V projection GEMM: grid (8, 32, 3), 512 threads.
// ---------------------------------------------------------------------------
struct QKVArgs {
    const u16* Ar[3]; const u16* Ai[3]; const u16* B2[3];
    const float* br[3]; const float* bi[3];
    u16* out[3];
    float oscale[3];
};

__launch_bounds__(512, 1)
__global__ void gemm_qkv(QKVArgs args) {
    __shared__ __attribute__((aligned(16))) u16 As3[3][128 * 64];
    __shared__ __attribute__((aligned(16))) u16 Bs3[3][256 * 64];

    const int z = blockIdx.z;
    const u16* __restrict__ Apr = args.Ar[z];
    const u16* __restrict__ Api = args.Ai[z];
    const u16* __restrict__ Bp  = args.B2[z];

    const int tid = threadIdx.x, wv = tid >> 6, lane = tid & 63;
    const int quad = lane >> 4, l16 = lane & 15;
    const int m0 = blockIdx.y * 128, n0 = blockIdx.x * 256;
    const int wr = wv >> 2, wc = wv & 3;   // 2M x 4N waves, 64x64 out each

    f32x4 acc[4][4] = {};
    bf16x8 afr[4][2];
    bf16x8 bfr[2][2];

    GEMM3_LOOP

    const float* __restrict__ br_ = args.br[z];
    const float* __restrict__ bi_ = args.bi[z];
    u16* __restrict__ out = args.out[z];
    const float oscale = args.oscale[z];

    #pragma unroll
    for (int j = 0; j < 4; j++) {
        int gn = n0 + (j >> 1) * 128 + wc * 32 + (j & 1) * 16 + l16;
        int ri = gn >> 10, e = gn & 1023;
        float bias = ri ? bi_[e] : br_[e];
        int h = e >> 6, d = e & 63;
        #pragma unroll
        for (int i = 0; i < 4; i++) {
            int gmb = m0 + wr * 64 + i * 16 + quad * 4;
            #pragma unroll
            for (int r = 0; r < 4; r++) {
                int gm = gmb + r;
                float v = (acc[i][j][r] + bias) * oscale;
                int b = gm >> 11, l = gm & 2047;
                if (z < 2)
                    out[((size_t)(b * HH + h) * LL + l) * 128 + ri * 64 + d] = f2bf(v);
                else
                    out[((size_t)(b * HH + h) * 128 + ri * 64 + d) * LL + l] = f2bf(v);
            }
        }
    }
}

// ---------------------------------------------------------------------------
// Output projection GEMM -> d_out fp32 [2][4096][1024]: grid (8, 32), 512 thr
// ---------------------------------------------------------------------------
__launch_bounds__(512, 1)
__global__ void gemm_oproj(const u16* __restrict__ Ar, const u16* __restrict__ Ai,
                           const u16* __restrict__ B2,
                           const float* __restrict__ br, const float* __restrict__ bi,
                           float* __restrict__ out)
{
    __shared__ __attribute__((aligned(16))) u16 As3[3][128 * 64];
    __shared__ __attribute__((aligned(16))) u16 Bs3[3][256 * 64];

    const u16* __restrict__ Apr = Ar;
    const u16* __restrict__ Api = Ai;
    const u16* __restrict__ Bp  = B2;

    const int tid = threadIdx.x, wv = tid >> 6, lane = tid & 63;
    const int quad = lane >> 4, l16 = lane & 15;
    const int m0 = blockIdx.y * 128, n0 = blockIdx.x * 256;
    const int wr = wv >> 2, wc = wv & 3;

    f32x4 acc[4][4] = {};
    bf16x8 afr[4][2];
    bf16x8 bfr[2][2];

    GEMM3_LOOP

    #pragma unroll
    for (int j = 0; j < 4; j++) {
        int gn = n0 + (j >> 1) * 128 + wc * 32 + (j & 1) * 16 + l16;
        int ri = gn >> 10, e = gn & 1023;
        float bias = ri ? bi[e] : br[e];
        #pragma unroll
        for (int i = 0; i < 4; i++) {
            int gmb = m0 + wr * 64 + i * 16 + quad * 4;
            #pragma unroll
            for (int r = 0; r < 4; r++) {
                int gm = gmb + r;
                out[ri * (BL * EE) + gm * EE + e] = acc[i][j][r] + bias;
            }
        }
    }
}

// ---------------------------------------------------------------------------
// Flash attention, BQ=64, grid flattened to 1024 with XCD-locality swizzle:
// xcd = bid&7, j = bid>>3, bh = xcd + 8*(j>>5), q0 = (j&31)*64.
// All 32 q-blocks of one bh stay on one XCD (consecutive bids round-robin
// XCDs) -> K/V panel cached once per L2, not 8x.
// Online softmax in log2 domain, math VERBATIM; P-pack via v_cvt_pk_bf16_f32.
// q_ws/k_ws: bf16 [bh][l][128] (Q pre-scaled by 0.125*log2e); v_ws: [bh][128][2048]
// ---------------------------------------------------------------------------
__launch_bounds__(256, 3)
__global__ void attn(const u16* __restrict__ q_ws, const u16* __restrict__ k_ws,
                     const u16* __restrict__ v_ws,
                     u16* __restrict__ o_r, u16* __restrict__ o_i)
{
    __shared__ __attribute__((aligned(16))) u16 kbuf[2][64 * 128];  // 2x16 KB
    __shared__ __attribute__((aligned(16))) u16 vbuf[128 * 64];     // 16 KB
    __shared__ __attribute__((aligned(16))) float red_sh[4][16];

    const int tid = threadIdx.x, wave = tid >> 6, lane = tid & 63;
    const int quad = lane >> 4, l16 = lane & 15;
    // XCD-locality swizzle (bijective on [0,1024))
    const int bid = blockIdx.x;
    const int xcd = bid & 7, jj = bid >> 3;
    const int bh = xcd + 8 * (jj >> 5);
    const int q0 = (jj & 31) * 64;

    // Q fragments (B-operand layout: row = l16, k = quad*8+j); wave owns 16 q rows
    bf16x8 qf[4];
    {
        const u16* qp = q_ws + (size_t)(bh * LL + q0 + wave * 16 + l16) * 128 + quad * 8;
        for (int ks = 0; ks < 4; ks++)
            qf[ks] = *(const bf16x8*)(qp + ks * 32);
    }

    auto stage_k = [&](int nb, int kv0) {
        for (int t = 0; t < 4; t++) {
            int s = wave * 4 + t;
            int row = s * 4 + (lane >> 4);
            int cg = (lane & 15) ^ (row & 15);
            gl2lds16(k_ws + (size_t)(bh * LL + kv0 + row) * 128 + cg * 8, &kbuf[nb][s * 512]);
        }
    };
    auto stage_v = [&](int kv0) {
        for (int t = 0; t < 4; t++) {
            int s = wave * 4 + t;
            int row = s * 8 + (lane >> 3);
            int cg = (lane & 7) ^ (row & 7);
            gl2lds16(v_ws + (size_t)(bh * 128 + row) * LL + kv0 + cg * 8, &vbuf[s * 512]);
        }
    };

    stage_k(0, 0);
    stage_v(0);
    stage_k(1, 64);
    __syncthreads();

    f32x4 oacc[8] = {};
    float m_st = -__builtin_inff();
    float l_st = 0.f;

    for (int N = 0; N < 32; N++) {
        const int cur = N & 1;
        u16* K = kbuf[cur];

        // ---- S^T[64 kv][16 q] = K . Q^T ----
        f32x4 s[4] = {};
        for (int ks = 0; ks < 4; ks++) {
            bf16x8 kf[4];
            for (int mt = 0; mt < 4; mt++) {
                int row = mt * 16 + l16;
                int cl = (ks * 4 + quad) ^ (row & 15);
                kf[mt] = *(const bf16x8*)&K[row * 128 + cl * 8];
            }
            for (int mt = 0; mt < 4; mt++)
                s[mt] = __builtin_amdgcn_mfma_f32_16x16x32_bf16(kf[mt], qf[ks], s[mt], 0, 0, 0);
        }

        // ---- online softmax (log2 domain); q = l16, kv = mt*16+quad*4+r ----
        bool changed = false;
        float alpha;
        {
            float mx = -__builtin_inff();
            for (int mt = 0; mt < 4; mt++)
                for (int r = 0; r < 4; r++)
                    mx = fmaxf(mx, s[mt][r]);
            mx = fmaxf(mx, __shfl_xor(mx, 16, 64));
            mx = fmaxf(mx, __shfl_xor(mx, 32, 64));
            float mnew = fmaxf(m_st, mx);
            changed = (mnew != m_st);
            alpha = __builtin_amdgcn_exp2f(m_st - mnew);
            m_st = mnew;
            float sum = 0.f;
            for (int mt = 0; mt < 4; mt++)
                for (int r = 0; r < 4; r++) {
                    float p = __builtin_amdgcn_exp2f(s[mt][r] - mnew);
                    s[mt][r] = p;
                    sum += p;
                }
            sum += __shfl_xor(sum, 16, 64);
            sum += __shfl_xor(sum, 32, 64);
            l_st = l_st * alpha + sum;
            if (quad == 0) red_sh[wave][l16] = alpha;
        }
        __syncthreads();   // barrier A: K[cur] reads done; drains prev async loads

        // ---- P (A-layout [16 q][64 kv]) into own slice of kbuf[cur] ----
        // v_cvt_pk_bf16_f32 = hardware RNE pack, bit-identical to f2bf here
        u16* P = kbuf[cur] + wave * 1024;
        for (int mt = 0; mt < 4; mt++) {
            int q = l16;
            int cg = mt * 2 + (quad >> 1);
            int cl = cg ^ (q & 7);
            unsigned lo, hi;
            asm("v_cvt_pk_bf16_f32 %0, %1, %2" : "=v"(lo) : "v"(s[mt][0]), "v"(s[mt][1]));
            asm("v_cvt_pk_bf16_f32 %0, %1, %2" : "=v"(hi) : "v"(s[mt][2]), "v"(s[mt][3]));
            uint2 pk2; pk2.x = lo; pk2.y = hi;
            *(uint2*)&P[q * 64 + cl * 8 + (quad & 1) * 4] = pk2;
        }

        // ---- O rescale (skip when running max unchanged wave-wide) ----
        if (__any(changed)) {
            f32x4 av = *(const f32x4*)&red_sh[wave][quad * 4];
            for (int nt = 0; nt < 8; nt++)
                oacc[nt] *= av;
        }

        // ---- O += P @ V ----
        for (int ks = 0; ks < 2; ks++) {
            int clp = (ks * 4 + quad) ^ (l16 & 7);
            bf16x8 pf = *(const bf16x8*)&P[l16 * 64 + clp * 8];
            for (int nt = 0; nt < 8; nt++) {
                int row = nt * 16 + l16;
                int cl = (ks * 4 + quad) ^ (row & 7);
                bf16x8 vf = *(const bf16x8*)&vbuf[row * 64 + cl * 8];
                oacc[nt] = __builtin_amdgcn_mfma_f32_16x16x32_bf16(pf, vf, oacc[nt], 0, 0, 0);
            }
        }
        __syncthreads();   // barrier B: PV done everywhere; P dead, vbuf free

        if (N + 2 < 32) stage_k(cur, (N + 2) * 64);   // into region P occupied
        if (N + 1 < 32) stage_v((N + 1) * 64);
    }

    // ---- epilogue: O /= l, write bf16 o_r/o_i [4096][1024] ----
    if (quad == 0) red_sh[wave][l16] = l_st;
    __syncthreads();
    f32x4 lv = *(const f32x4*)&red_sh[wave][quad * 4];
    f32x4 inv;
    for (int r = 0; r < 4; r++) inv[r] = 1.0f / lv[r];
    const int b = bh >> 4, h = bh & 15;
    for (int nt = 0; nt < 8; nt++) {
        int d2 = nt * 16 + l16;
        u16* op = (d2 < 64) ? o_r : o_i;
        int col = h * 64 + (d2 & 63);
        for (int r = 0; r < 4; r++) {
            int l = q0 + wave * 16 + quad * 4 + r;
            op[(size_t)(b * LL + l) * EE + col] = f2bf(oacc[nt][r] * inv[r]);
        }
    }
}

// ---------------------------------------------------------------------------
extern "C" void kernel_launch(void* const* d_in, const int* in_sizes, int n_in,
                              void* d_out, int out_size, void* d_ws, size_t ws_size,
                              hipStream_t stream) {
    const float* bq_r = (const float*)d_in[8];
    const float* bq_i = (const float*)d_in[9];
    const float* bk_r = (const float*)d_in[12];
    const float* bk_i = (const float*)d_in[13];
    const float* bv_r = (const float*)d_in[16];
    const float* bv_i = (const float*)d_in[17];
    const float* bo_r = (const float*)d_in[20];
    const float* bo_i = (const float*)d_in[21];

    u16* ws = (u16*)d_ws;
    const size_t XN = 4194304;          // 4096*1024 elements (= 2048*2048)
    u16* xqr = ws;            u16* xqi = xqr + XN;
    u16* xkr = xqi + XN;      u16* xki = xkr + XN;
    u16* xvr = xki + XN;      u16* xvi = xvr + XN;
    u16* w2q = xvi + XN;
    u16* w2k = w2q + XN;
    u16* w2v = w2k + XN;
    u16* w2o = w2v + XN;
    u16* q_ws = w2o + XN;               // 32*2048*128 = 8,388,608
    u16* k_ws = q_ws + 8388608;
    u16* v_ws = k_ws + 8388608;
    u16* o_r = xqr;                     // X regions dead after QKV GEMMs
    u16* o_i = xqr + XN;

    dim3 blk(256);

    ConvXArgs cx;
    cx.src[0] = (const float*)d_in[0]; cx.dst[0] = xqr;
    cx.src[1] = (const float*)d_in[1]; cx.dst[1] = xqi;
    cx.src[2] = (const float*)d_in[2]; cx.dst[2] = xkr;
    cx.src[3] = (const float*)d_in[3]; cx.dst[3] = xki;
    cx.src[4] = (const float*)d_in[4]; cx.dst[4] = xvr;
    cx.src[5] = (const float*)d_in[5]; cx.dst[5] = xvi;
    conv_x<<<dim3(4096, 6), blk, 0, stream>>>(cx);

    ConvWArgs cw;
    cw.wr[0] = (const float*)d_in[6];  cw.wi[0] = (const float*)d_in[7];  cw.w2[0] = w2q;
    cw.wr[1] = (const float*)d_in[10]; cw.wi[1] = (const float*)d_in[11]; cw.w2[1] = w2k;
    cw.wr[2] = (const float*)d_in[14]; cw.wi[2] = (const float*)d_in[15]; cw.w2[2] = w2v;
    cw.wr[3] = (const float*)d_in[18]; cw.wi[3] = (const float*)d_in[19]; cw.w2[3] = w2o;
    conv_w<<<dim3(4096, 4), blk, 0, stream>>>(cw);

    const float QSCALE = 0.125f * 1.44269504088896f;   // 1/sqrt(D) * log2(e)
    QKVArgs qa;
    qa.Ar[0] = xqr; qa.Ai[0] = xqi; qa.B2[0] = w2q; qa.br[0] = bq_r; qa.bi[0] = bq_i; qa.out[0] = q_ws; qa.oscale[0] = QSCALE;
    qa.Ar[1] = xkr; qa.Ai[1] = xki; qa.B2[1] = w2k; qa.br[1] = bk_r; qa.bi[1] = bk_i; qa.out[1] = k_ws; qa.oscale[1] = 1.0f;
    qa.Ar[2] = xvr; qa.Ai[2] = xvi; qa.B2[2] = w2v; qa.br[2] = bv_r; qa.bi[2] = bv_i; qa.out[2] = v_ws; qa.oscale[2] = 1.0f;
    gemm_qkv<<<dim3(8, 32, 3), dim3(512), 0, stream>>>(qa);

    attn<<<dim3(1024), blk, 0, stream>>>(q_ws, k_ws, v_ws, o_r, o_i);

    gemm_oproj<<<dim3(8, 32), dim3(512), 0, stream>>>(o_r, o_i, w2o, bo_r, bo_i, (float*)d_out);
}

// Round 5
// 452.146 us; speedup vs baseline: 1.0785x; 1.0785x over previous
//
#include <hip/hip_runtime.h>

// ComplexMultiheadAttention on MI355X (gfx950)  B=2, L=2048, E=1024, H=16, D=64
// R11: attn BQ 64 -> 128 with 512 threads / 8 waves (16 q-rows per wave,
// per-wave math VERBATIM). K/V staged once per 128 q (traffic + staging
// instrs halve), MFMA per barrier-pair doubles, grid (16,32)=512 blocks all
// resident (2 blocks/CU, 16 waves/CU). R10's XCD swizzle reverted (neutral
// within +/-2-3% bench drift); cvt_pk P-pack kept (bit-identical).
// gemm_qkv / gemm_oproj / conv_x / conv_w unchanged from R9.

#define LL 2048
#define EE 1024
#define HH 16
#define BL 4096   // B*L
#define KK 2048   // GEMM K (re||im)

typedef __attribute__((ext_vector_type(8))) short bf16x8;
typedef __attribute__((ext_vector_type(4))) float f32x4;
typedef unsigned short u16;

__device__ __forceinline__ u16 f2bf(float x) {
    unsigned u = __builtin_bit_cast(unsigned, x);
    u += 0x7fff + ((u >> 16) & 1);          // RNE
    return (u16)(u >> 16);
}

__device__ __forceinline__ void gl2lds16(const void* g, void* l) {
    __builtin_amdgcn_global_load_lds((const __attribute__((address_space(1))) void*)g,
                                     (__attribute__((address_space(3))) void*)l, 16, 0, 0);
}

// ---------------------------------------------------------------------------
// Merged fp32->bf16 conversion: 6 activation tensors, grid (4096, 6)
// ---------------------------------------------------------------------------
struct ConvXArgs { const float* src[6]; u16* dst[6]; };
__global__ void conv_x(ConvXArgs a) {
    const int z = blockIdx.y;
    int i = blockIdx.x * 256 + threadIdx.x;     // 1,048,576 float4 groups exactly
    float4 v = ((const float4*)a.src[z])[i];
    ushort4 o;
    o.x = f2bf(v.x); o.y = f2bf(v.y); o.z = f2bf(v.z); o.w = f2bf(v.w);
    ((ushort4*)a.dst[z])[i] = o;
}

// ---------------------------------------------------------------------------
// Merged W2 build: 4 weight pairs, grid (4096, 4)
// W2 bf16 [2048 n][2048 k]: n<1024: [Wr | -Wi] ; n>=1024: [Wi | Wr]
// ---------------------------------------------------------------------------
struct ConvWArgs { const float* wr[4]; const float* wi[4]; u16* w2[4]; };
__global__ void conv_w(ConvWArgs a) {
    const int z = blockIdx.y;
    int i = blockIdx.x * 256 + threadIdx.x;     // 2048*512 groups exactly
    int n = i >> 9, k = (i & 511) << 2;
    bool nh = n >= EE, kh = k >= EE;
    int nn = n & (EE - 1), kk = k & (EE - 1);
    const float* src = nh ? (kh ? a.wr[z] : a.wi[z]) : (kh ? a.wi[z] : a.wr[z]);
    float sgn = (!nh && kh) ? -1.0f : 1.0f;
    float4 v = *(const float4*)(src + nn * EE + kk);
    ushort4 o;
    o.x = f2bf(v.x * sgn); o.y = f2bf(v.y * sgn);
    o.z = f2bf(v.z * sgn); o.w = f2bf(v.w * sgn);
    *(ushort4*)(a.w2[z] + n * KK + k) = o;
}

// ---------------------------------------------------------------------------
// Shared 128x256 triple-buffered GEMM K-loop (R9, unchanged).
// LDS: As3[3][128*64] (16 KB/buf) + Bs3[3][256*64] (32 KB/buf) = 144 KiB.
// 512 threads = 8 waves as 2M x 4N; wave tile 64x64 = acc[4][4].
// ---------------------------------------------------------------------------
#define BAR      asm volatile("s_barrier" ::: "memory")
#define BARW(N)  asm volatile("s_waitcnt vmcnt(" #N ")\n\ts_barrier" ::: "memory")

#define S_A(B, K0)                                                             \
    { const u16* S_ = ((K0) < EE) ? (Apr + (K0)) : (Api + ((K0) - EE));        \
      int rl_ = wv * 8 + (lane >> 3);                                          \
      int cg_ = ((lane & 7) ^ (lane >> 3)) * 8;                                \
      gl2lds16(S_ + (size_t)(m0 + rl_) * EE + cg_, &As3[B][wv * 512]);         \
      gl2lds16(S_ + (size_t)(m0 + rl_ + 64) * EE + cg_, &As3[B][wv * 512 + 4096]); }

#define S_B(B, H, K0)                                                          \
    { const u16* S_ = Bp + (K0);                                               \
      int rl_ = wv * 8 + (lane >> 3);                                          \
      int cg_ = ((lane & 7) ^ (lane >> 3)) * 8;                                \
      gl2lds16(S_ + (size_t)(n0 + (H) * 128 + rl_) * (size_t)KK + cg_,         \
               &Bs3[B][(H) * 8192 + wv * 512]);                                \
      gl2lds16(S_ + (size_t)(n0 + (H) * 128 + rl_ + 64) * (size_t)KK + cg_,    \
               &Bs3[B][(H) * 8192 + wv * 512 + 4096]); }

#define L_A(B)                                                                 \
    _Pragma("unroll") for (int i_ = 0; i_ < 4; i_++) {                         \
        int row_ = wr * 64 + i_ * 16 + l16;                                    \
        _Pragma("unroll") for (int s_ = 0; s_ < 2; s_++) {                     \
            int ph_ = (s_ * 4 + quad) ^ (l16 & 7);                             \
            afr[i_][s_] = *(const bf16x8*)&As3[B][row_ * 64 + ph_ * 8]; } }

#define L_B(B, H)                                                              \
    _Pragma("unroll") for (int j_ = 0; j_ < 2; j_++) {                         \
        int row_ = wc * 32 + j_ * 16 + l16;                                    \
        _Pragma("unroll") for (int s_ = 0; s_ < 2; s_++) {                     \
            int ph_ = (s_ * 4 + quad) ^ (l16 & 7);                             \
            bfr[j_][s_] = *(const bf16x8*)&Bs3[B][(H) * 8192 + row_ * 64 + ph_ * 8]; } }

#define MMA_H(H)                                                               \
    { __builtin_amdgcn_s_setprio(1);                                           \
      _Pragma("unroll") for (int s_ = 0; s_ < 2; s_++)                         \
          _Pragma("unroll") for (int i_ = 0; i_ < 4; i_++)                     \
              _Pragma("unroll") for (int j_ = 0; j_ < 2; j_++)                 \
                  acc[i_][(H) * 2 + j_] =                                      \
                      __builtin_amdgcn_mfma_f32_16x16x32_bf16(                 \
                          afr[i_][s_], bfr[j_][s_], acc[i_][(H) * 2 + j_], 0, 0, 0); \
      __builtin_amdgcn_s_setprio(0); }

#define GITER(B, NB, KN)                                                       \
    {   L_A(B); L_B(B, 0);                                                     \
        S_A(NB, KN); S_B(NB, 0, KN);                                           \
        BAR;                                                                   \
        MMA_H(0);                                                              \
        L_B(B, 1);                                                             \
        S_B(NB, 1, KN);                                                        \
        BAR;                                                                   \
        MMA_H(1);                                                              \
        BARW(6); }

#define GEMM3_LOOP                                                             \
    S_A(0, 0);  S_B(0, 0, 0);  S_B(0, 1, 0);                                   \
    S_A(1, 64); S_B(1, 0, 64); S_B(1, 1, 64);                                  \
    BARW(6);                                                                   \
    for (int t3 = 0; t3 < 10; t3++) {                                          \
        const int kb = t3 * 192;                                               \
        GITER(0, 2, kb + 128);                                                 \
        GITER(1, 0, kb + 192);                                                 \
        GITER(2, 1, kb + 256);                                                 \
    }                                                                          \
    { L_A(0); L_B(0, 0); MMA_H(0); L_B(0, 1); MMA_H(1); }                      \
    BARW(0);                                                                   \
    { L_A(1); L_B(1, 0); MMA_H(0); L_B(1, 1); MMA_H(1); }

// ---------------------------------------------------------------------------
// Merged Q/K/V projection GEMM: grid (8, 32, 3), 512 threads.
// ---------------------------------------------------------------------------
struct QKVArgs {
    const u16* Ar[3]; const u16* Ai[3]; const u16* B2[3];
    const float* br[3]; const float* bi[3];
    u16* out[3];
    float oscale[3];
};

__launch_bounds__(512, 1)
__global__ void gemm_qkv(QKVArgs args) {
    __shared__ __attribute__((aligned(16))) u16 As3[3][128 * 64];
    __shared__ __attribute__((aligned(16))) u16 Bs3[3][256 * 64];

    const int z = blockIdx.z;
    const u16* __restrict__ Apr = args.Ar[z];
    const u16* __restrict__ Api = args.Ai[z];
    const u16* __restrict__ Bp  = args.B2[z];

    const int tid = threadIdx.x, wv = tid >> 6, lane = tid & 63;
    const int quad = lane >> 4, l16 = lane & 15;
    const int m0 = blockIdx.y * 128, n0 = blockIdx.x * 256;
    const int wr = wv >> 2, wc = wv & 3;   // 2M x 4N waves, 64x64 out each

    f32x4 acc[4][4] = {};
    bf16x8 afr[4][2];
    bf16x8 bfr[2][2];

    GEMM3_LOOP

    const float* __restrict__ br_ = args.br[z];
    const float* __restrict__ bi_ = args.bi[z];
    u16* __restrict__ out = args.out[z];
    const float oscale = args.oscale[z];

    #pragma unroll
    for (int j = 0; j < 4; j++) {
        int gn = n0 + (j >> 1) * 128 + wc * 32 + (j & 1) * 16 + l16;
        int ri = gn >> 10, e = gn & 1023;
        float bias = ri ? bi_[e] : br_[e];
        int h = e >> 6, d = e & 63;
        #pragma unroll
        for (int i = 0; i < 4; i++) {
            int gmb = m0 + wr * 64 + i * 16 + quad * 4;
            #pragma unroll
            for (int r = 0; r < 4; r++) {
                int gm = gmb + r;
                float v = (acc[i][j][r] + bias) * oscale;
                int b = gm >> 11, l = gm & 2047;
                if (z < 2)
                    out[((size_t)(b * HH + h) * LL + l) * 128 + ri * 64 + d] = f2bf(v);
                else
                    out[((size_t)(b * HH + h) * 128 + ri * 64 + d) * LL + l] = f2bf(v);
            }
        }
    }
}

// ---------------------------------------------------------------------------
// Output projection GEMM -> d_out fp32 [2][4096][1024]: grid (8, 32), 512 thr
// ---------------------------------------------------------------------------
__launch_bounds__(512, 1)
__global__ void gemm_oproj(const u16* __restrict__ Ar, const u16* __restrict__ Ai,
                           const u16* __restrict__ B2,
                           const float* __restrict__ br, const float* __restrict__ bi,
                           float* __restrict__ out)
{
    __shared__ __attribute__((aligned(16))) u16 As3[3][128 * 64];
    __shared__ __attribute__((aligned(16))) u16 Bs3[3][256 * 64];

    const u16* __restrict__ Apr = Ar;
    const u16* __restrict__ Api = Ai;
    const u16* __restrict__ Bp  = B2;

    const int tid = threadIdx.x, wv = tid >> 6, lane = tid & 63;
    const int quad = lane >> 4, l16 = lane & 15;
    const int m0 = blockIdx.y * 128, n0 = blockIdx.x * 256;
    const int wr = wv >> 2, wc = wv & 3;

    f32x4 acc[4][4] = {};
    bf16x8 afr[4][2];
    bf16x8 bfr[2][2];

    GEMM3_LOOP

    #pragma unroll
    for (int j = 0; j < 4; j++) {
        int gn = n0 + (j >> 1) * 128 + wc * 32 + (j & 1) * 16 + l16;
        int ri = gn >> 10, e = gn & 1023;
        float bias = ri ? bi[e] : br[e];
        #pragma unroll
        for (int i = 0; i < 4; i++) {
            int gmb = m0 + wr * 64 + i * 16 + quad * 4;
            #pragma unroll
            for (int r = 0; r < 4; r++) {
                int gm = gmb + r;
                out[ri * (BL * EE) + gm * EE + e] = acc[i][j][r] + bias;
            }
        }
    }
}

// ---------------------------------------------------------------------------
// Flash attention, BQ=128, 512 threads / 8 waves (16 q rows per wave),
// grid (16, 32): all 512 blocks resident (2/CU). Transposed-S, online
// softmax in log2 domain (per-wave math VERBATIM from the known-good R2).
// K/V staged once per 128 q rows; P slices = 8 x 1KB = all of kbuf[cur].
// q_ws/k_ws: bf16 [bh][l][128] (Q pre-scaled by 0.125*log2e); v_ws: [bh][128][2048]
// ---------------------------------------------------------------------------
__launch_bounds__(512, 4)
__global__ void attn(const u16* __restrict__ q_ws, const u16* __restrict__ k_ws,
                     const u16* __restrict__ v_ws,
                     u16* __restrict__ o_r, u16* __restrict__ o_i)
{
    __shared__ __attribute__((aligned(16))) u16 kbuf[2][64 * 128];  // 2x16 KB
    __shared__ __attribute__((aligned(16))) u16 vbuf[128 * 64];     // 16 KB
    __shared__ __attribute__((aligned(16))) float red_sh[8][16];

    const int tid = threadIdx.x, wave = tid >> 6, lane = tid & 63;
    const int quad = lane >> 4, l16 = lane & 15;
    const int q0 = blockIdx.x * 128, bh = blockIdx.y;

    // Q fragments (B-operand layout: row = l16, k = quad*8+j); wave owns 16 q rows
    bf16x8 qf[4];
    {
        const u16* qp = q_ws + (size_t)(bh * LL + q0 + wave * 16 + l16) * 128 + quad * 8;
        for (int ks = 0; ks < 4; ks++)
            qf[ks] = *(const bf16x8*)(qp + ks * 32);
    }

    // staging at 512 threads: 2 gl2lds/thread each (16 segments, s = wave*2+t)
    auto stage_k = [&](int nb, int kv0) {
        for (int t = 0; t < 2; t++) {
            int s = wave * 2 + t;
            int row = s * 4 + (lane >> 4);
            int cg = (lane & 15) ^ (row & 15);
            gl2lds16(k_ws + (size_t)(bh * LL + kv0 + row) * 128 + cg * 8, &kbuf[nb][s * 512]);
        }
    };
    auto stage_v = [&](int kv0) {
        for (int t = 0; t < 2; t++) {
            int s = wave * 2 + t;
            int row = s * 8 + (lane >> 3);
            int cg = (lane & 7) ^ (row & 7);
            gl2lds16(v_ws + (size_t)(bh * 128 + row) * LL + kv0 + cg * 8, &vbuf[s * 512]);
        }
    };

    stage_k(0, 0);
    stage_v(0);
    stage_k(1, 64);
    __syncthreads();

    f32x4 oacc[8] = {};
    float m_st = -__builtin_inff();
    float l_st = 0.f;

    for (int N = 0; N < 32; N++) {
        const int cur = N & 1;
        u16* K = kbuf[cur];

        // ---- S^T[64 kv][16 q] = K . Q^T ----
        f32x4 s[4] = {};
        for (int ks = 0; ks < 4; ks++) {
            bf16x8 kf[4];
            for (int mt = 0; mt < 4; mt++) {
                int row = mt * 16 + l16;
                int cl = (ks * 4 + quad) ^ (row & 15);
                kf[mt] = *(const bf16x8*)&K[row * 128 + cl * 8];
            }
            for (int mt = 0; mt < 4; mt++)
                s[mt] = __builtin_amdgcn_mfma_f32_16x16x32_bf16(kf[mt], qf[ks], s[mt], 0, 0, 0);
        }

        // ---- online softmax (log2 domain); q = l16, kv = mt*16+quad*4+r ----
        bool changed = false;
        float alpha;
        {
            float mx = -__builtin_inff();
            for (int mt = 0; mt < 4; mt++)
                for (int r = 0; r < 4; r++)
                    mx = fmaxf(mx, s[mt][r]);
            mx = fmaxf(mx, __shfl_xor(mx, 16, 64));
            mx = fmaxf(mx, __shfl_xor(mx, 32, 64));
            float mnew = fmaxf(m_st, mx);
            changed = (mnew != m_st);
            alpha = __builtin_amdgcn_exp2f(m_st - mnew);
            m_st = mnew;
            float sum = 0.f;
            for (int mt = 0; mt < 4; mt++)
                for (int r = 0; r < 4; r++) {
                    float p = __builtin_amdgcn_exp2f(s[mt][r] - mnew);
                    s[mt][r] = p;
                    sum += p;
                }
            sum += __shfl_xor(sum, 16, 64);
            sum += __shfl_xor(sum, 32, 64);
            l_st = l_st * alpha + sum;
            if (quad == 0) red_sh[wave][l16] = alpha;
        }
        __syncthreads();   // barrier A: K[cur] reads done; drains prev async loads

        // ---- P (A-layout [16 q][64 kv]) into own slice of kbuf[cur] ----
        // v_cvt_pk_bf16_f32 = hardware RNE pack, bit-identical to f2bf here
        u16* P = kbuf[cur] + wave * 1024;
        for (int mt = 0; mt < 4; mt++) {
            int q = l16;
            int cg = mt * 2 + (quad >> 1);
            int cl = cg ^ (q & 7);
            unsigned lo, hi;
            asm("v_cvt_pk_bf16_f32 %0, %1, %2" : "=v"(lo) : "v"(s[mt][0]), "v"(s[mt][1]));
            asm("v_cvt_pk_bf16_f32 %0, %1, %2" : "=v"(hi) : "v"(s[mt][2]), "v"(s[mt][3]));
            uint2 pk2; pk2.x = lo; pk2.y = hi;
            *(uint2*)&P[q * 64 + cl * 8 + (quad & 1) * 4] = pk2;
        }

        // ---- O rescale (skip when running max unchanged wave-wide) ----
        if (__any(changed)) {
            f32x4 av = *(const f32x4*)&red_sh[wave][quad * 4];
            for (int nt = 0; nt < 8; nt++)
                oacc[nt] *= av;
        }

        // ---- O += P @ V ----
        for (int ks = 0; ks < 2; ks++) {
            int clp = (ks * 4 + quad) ^ (l16 & 7);
            bf16x8 pf = *(const bf16x8*)&P[l16 * 64 + clp * 8];
            for (int nt = 0; nt < 8; nt++) {
                int row = nt * 16 + l16;
                int cl = (ks * 4 + quad) ^ (row & 7);
                bf16x8 vf = *(const bf16x8*)&vbuf[row * 64 + cl * 8];
                oacc[nt] = __builtin_amdgcn_mfma_f32_16x16x32_bf16(pf, vf, oacc[nt], 0, 0, 0);
            }
        }
        __syncthreads();   // barrier B: PV done everywhere; P dead, vbuf free

        if (N + 2 < 32) stage_k(cur, (N + 2) * 64);   // into region P occupied
        if (N + 1 < 32) stage_v((N + 1) * 64);
    }

    // ---- epilogue: O /= l, write bf16 o_r/o_i [4096][1024] ----
    if (quad == 0) red_sh[wave][l16] = l_st;
    __syncthreads();
    f32x4 lv = *(const f32x4*)&red_sh[wave][quad * 4];
    f32x4 inv;
    for (int r = 0; r < 4; r++) inv[r] = 1.0f / lv[r];
    const int b = bh >> 4, h = bh & 15;
    for (int nt = 0; nt < 8; nt++) {
        int d2 = nt * 16 + l16;
        u16* op = (d2 < 64) ? o_r : o_i;
        int col = h * 64 + (d2 & 63);
        for (int r = 0; r < 4; r++) {
            int l = q0 + wave * 16 + quad * 4 + r;
            op[(size_t)(b * LL + l) * EE + col] = f2bf(oacc[nt][r] * inv[r]);
        }
    }
}

// ---------------------------------------------------------------------------
extern "C" void kernel_launch(void* const* d_in, const int* in_sizes, int n_in,
                              void* d_out, int out_size, void* d_ws, size_t ws_size,
                              hipStream_t stream) {
    const float* bq_r = (const float*)d_in[8];
    const float* bq_i = (const float*)d_in[9];
    const float* bk_r = (const float*)d_in[12];
    const float* bk_i = (const float*)d_in[13];
    const float* bv_r = (const float*)d_in[16];
    const float* bv_i = (const float*)d_in[17];
    const float* bo_r = (const float*)d_in[20];
    const float* bo_i = (const float*)d_in[21];

    u16* ws = (u16*)d_ws;
    const size_t XN = 4194304;          // 4096*1024 elements (= 2048*2048)
    u16* xqr = ws;            u16* xqi = xqr + XN;
    u16* xkr = xqi + XN;      u16* xki = xkr + XN;
    u16* xvr = xki + XN;      u16* xvi = xvr + XN;
    u16* w2q = xvi + XN;
    u16* w2k = w2q + XN;
    u16* w2v = w2k + XN;
    u16* w2o = w2v + XN;
    u16* q_ws = w2o + XN;               // 32*2048*128 = 8,388,608
    u16* k_ws = q_ws + 8388608;
    u16* v_ws = k_ws + 8388608;
    u16* o_r = xqr;                     // X regions dead after QKV GEMMs
    u16* o_i = xqr + XN;

    dim3 blk(256);

    ConvXArgs cx;
    cx.src[0] = (const float*)d_in[0]; cx.dst[0] = xqr;
    cx.src[1] = (const float*)d_in[1]; cx.dst[1] = xqi;
    cx.src[2] = (const float*)d_in[2]; cx.dst[2] = xkr;
    cx.src[3] = (const float*)d_in[3]; cx.dst[3] = xki;
    cx.src[4] = (const float*)d_in[4]; cx.dst[4] = xvr;
    cx.src[5] = (const float*)d_in[5]; cx.dst[5] = xvi;
    conv_x<<<dim3(4096, 6), blk, 0, stream>>>(cx);

    ConvWArgs cw;
    cw.wr[0] = (const float*)d_in[6];  cw.wi[0] = (const float*)d_in[7];  cw.w2[0] = w2q;
    cw.wr[1] = (const float*)d_in[10]; cw.wi[1] = (const float*)d_in[11]; cw.w2[1] = w2k;
    cw.wr[2] = (const float*)d_in[14]; cw.wi[2] = (const float*)d_in[15]; cw.w2[2] = w2v;
    cw.wr[3] = (const float*)d_in[18]; cw.wi[3] = (const float*)d_in[19]; cw.w2[3] = w2o;
    conv_w<<<dim3(4096, 4), blk, 0, stream>>>(cw);

    const float QSCALE = 0.125f * 1.44269504088896f;   // 1/sqrt(D) * log2(e)
    QKVArgs qa;
    qa.Ar[0] = xqr; qa.Ai[0] = xqi; qa.B2[0] = w2q; qa.br[0] = bq_r; qa.bi[0] = bq_i; qa.out[0] = q_ws; qa.oscale[0] = QSCALE;
    qa.Ar[1] = xkr; qa.Ai[1] = xki; qa.B2[1] = w2k; qa.br[1] = bk_r; qa.bi[1] = bk_i; qa.out[1] = k_ws; qa.oscale[1] = 1.0f;
    qa.Ar[2] = xvr; qa.Ai[2] = xvi; qa.B2[2] = w2v; qa.br[2] = bv_r; qa.bi[2] = bv_i; qa.out[2] = v_ws; qa.oscale[2] = 1.0f;
    gemm_qkv<<<dim3(8, 32, 3), dim3(512), 0, stream>>>(qa);

    attn<<<dim3(16, 32), dim3(512), 0, stream>>>(q_ws, k_ws, v_ws, o_r, o_i);

    gemm_oproj<<<dim3(8, 32), dim3(512), 0, stream>>>(o_r, o_i, w2o, bo_r, bo_i, (float*)d_out);
}